// Round 5
// baseline (239.251 us; speedup 1.0000x reference)
//
#include <hip/hip_runtime.h>

// LIF scan: u = 0.5*u + x_t; o = (u > 1); u = 0 where spiked. Bit-exact.
// x: [B=32, T=128, N=8192] fp32; out same, values in {0,1}.
//
// R4 lesson: LDS double-buffer staging beat the register-chain scheduling trap
// (kernel fell out of rocprof top-5, <79us). Remaining coupling: 4 waves/block
// share one barrier that drains ALL vmcnt (prefetch + stores) together.
// R5: single-wave (64-thread) blocks -> 4096 blocks = 16 independent
// pipelines/CU, decorrelated drains; __syncthreads in a 1-wave group lowers to
// just s_waitcnt. 64-col tile => t-row = 256B, staged with global_load_lds
// size=4 (64 lanes x 4B = one coalesced 256B row). Consumption is lane-local.
// LDS 8KB/block x 16 blocks/CU = 128KB <= 160KB.

constexpr int B  = 32;
constexpr int T  = 128;
constexpr int N  = 8192;
constexpr int NW = 64;        // columns per block == block size (1 wave)
constexpr int TC = 16;        // timesteps per staged chunk
constexpr int NC = T / TC;    // 8 chunks

__device__ __forceinline__ void async4(void* lds_dst, const void* g_src) {
    __builtin_amdgcn_global_load_lds(
        (const __attribute__((address_space(1))) void*)g_src,
        (__attribute__((address_space(3))) void*)lds_dst, 4, 0, 0);
}

__global__ __launch_bounds__(64) void lif_kernel(const float* __restrict__ x,
                                                 float* __restrict__ out) {
    __shared__ float buf[2][TC][NW];              // 8 KB

    const int tid   = threadIdx.x;                // == lane
    const int b     = blockIdx.x >> 7;            // N/NW = 128 tiles per batch row
    const int ntile = blockIdx.x & 127;
    const size_t base = (size_t)b * T * N + (size_t)ntile * NW;
    const float* xp = x + base;                   // + t*N + lane
    float*       op = out + base + tid;

    // stage chunk 0: 16 rows, each one 256B coalesced async row-load
    #pragma unroll
    for (int j = 0; j < TC; ++j)
        async4(&buf[0][j][tid], xp + (size_t)j * N + tid);

    float u = 0.f;
    #pragma unroll
    for (int c = 0; c < NC; ++c) {
        __syncthreads();          // 1-wave group: lowers to the vmcnt drain only
        if (c + 1 < NC) {         // prefetch next chunk into other buffer
            const float* g = xp + (size_t)(c + 1) * TC * N;
            #pragma unroll
            for (int j = 0; j < TC; ++j)
                async4(&buf[(c + 1) & 1][j][tid], g + (size_t)j * N + tid);
        }
        const float* lb = &buf[c & 1][0][0];
        float* o = op + (size_t)c * TC * N;
        #pragma unroll
        for (int t = 0; t < TC; ++t) {
            const float xt = lb[t * NW + tid];    // lane-local, 2-way alias (free)
            u = 0.5f * u + xt;
            const float sp = (u > 1.0f) ? 1.0f : 0.0f;
            u = (u > 1.0f) ? 0.0f : u;
            o[(size_t)t * N] = sp;                // 64 lanes x 4B = 256B coalesced
        }
    }
}

extern "C" void kernel_launch(void* const* d_in, const int* in_sizes, int n_in,
                              void* d_out, int out_size, void* d_ws, size_t ws_size,
                              hipStream_t stream) {
    const float* x  = (const float*)d_in[0];
    float*      out = (float*)d_out;
    const int nblocks = B * (N / NW);             // 32 * 128 = 4096
    lif_kernel<<<nblocks, NW, 0, stream>>>(x, out);
}

// Round 6
// 233.776 us; speedup vs baseline: 1.0234x; 1.0234x over previous
//
#include <hip/hip_runtime.h>
#include <stdint.h>

// LIF scan: u = 0.5*u + x_t; o = (u > 1); u = 0 where spiked. Bit-exact.
// x: [B=32, T=128, N=8192] fp32; out same, values in {0,1}.
//
// R5 lesson: __syncthreads' vmcnt(0) drains EVERYTHING (newest prefetch +
// all compute-loop stores) -> pipeline depth is structurally 1; single-wave
// blocks regressed to 2.3 TB/s. R4 (256-thr, async16, 2x16KB) was best (<79us).
// R6 = R4 + stores removed from the drain: pack spikes as bits in 4 VGPRs,
// burst-store everything at the end (pure write phase runs ~6.7 TB/s per the
// harness fill kernels). Scan barriers now drain only the 16KB prefetch.

constexpr int B   = 32;
constexpr int T   = 128;
constexpr int N   = 8192;
constexpr int N4  = N / 4;       // 2048 float4 per (b,t) row
constexpr int TC  = 16;          // timesteps per staged chunk
constexpr int NC  = T / TC;      // 8 chunks
constexpr int NW4 = 64;          // float4 columns per block = 256 floats

__device__ __forceinline__ void async16(void* lds_dst, const void* g_src) {
    __builtin_amdgcn_global_load_lds(
        (const __attribute__((address_space(1))) void*)g_src,
        (__attribute__((address_space(3))) void*)lds_dst, 16, 0, 0);
}

__global__ __launch_bounds__(256) void lif_kernel(const float4* __restrict__ x,
                                                  float* __restrict__ out) {
    __shared__ float4 buf[2][TC][NW4];            // 2 x 16 KB

    const int tid   = threadIdx.x;
    const int wave  = tid >> 6;
    const int lane  = tid & 63;
    const int b     = blockIdx.x >> 5;            // 32 n-tiles per batch row
    const int ntile = blockIdx.x & 31;
    const size_t xbase4 = (size_t)b * T * N4 + (size_t)ntile * NW4;   // float4 units
    const size_t obase  = (size_t)b * T * N  + (size_t)ntile * (NW4 * 4) + tid;

    // stage chunk 0 (identical to R4): 16 t-rows x 64 float4, async16,
    // LDS dest = wave-uniform base + lane*16.
    {
        const float4* g0 = x + xbase4;
        #pragma unroll
        for (int k = 0; k < TC / 4; ++k) {
            const int t_sub = k * 4 + wave;
            async16(&buf[0][t_sub][lane], g0 + (size_t)t_sub * N4 + lane);
        }
    }

    float u = 0.f;
    uint32_t sw[4] = {0u, 0u, 0u, 0u};            // 128 spike bits

    #pragma unroll
    for (int c = 0; c < NC; ++c) {
        __syncthreads();          // drains ONLY the in-flight prefetch now
        if (c + 1 < NC) {
            const float4* g = x + xbase4 + (size_t)(c + 1) * TC * N4;
            #pragma unroll
            for (int k = 0; k < TC / 4; ++k) {
                const int t_sub = k * 4 + wave;
                async16(&buf[(c + 1) & 1][t_sub][lane], g + (size_t)t_sub * N4 + lane);
            }
        }
        const float* lb = (const float*)buf[c & 1];
        #pragma unroll
        for (int t = 0; t < TC; ++t) {            // no global stores in scan
            const float xt = lb[t * 256 + tid];   // lane-local, 2-way alias (free)
            u = 0.5f * u + xt;
            const uint32_t bit = (u > 1.0f) ? 1u : 0u;
            sw[c >> 1] |= bit << ((c & 1) * 16 + t);   // compile-time shift
            u = (u > 1.0f) ? 0.0f : u;
        }
    }

    // burst store: 128 independent coalesced 256B stores per wave
    #pragma unroll
    for (int t = 0; t < T; ++t) {
        const float sp = ((sw[t >> 5] >> (t & 31)) & 1u) ? 1.0f : 0.0f;
        out[obase + (size_t)t * N] = sp;
    }
}

extern "C" void kernel_launch(void* const* d_in, const int* in_sizes, int n_in,
                              void* d_out, int out_size, void* d_ws, size_t ws_size,
                              hipStream_t stream) {
    const float4* x  = (const float4*)d_in[0];
    float*      out = (float*)d_out;
    const int nblocks = B * (N / (NW4 * 4));      // 32 * 32 = 1024
    lif_kernel<<<nblocks, 256, 0, stream>>>(x, out);
}

// Round 7
// 229.989 us; speedup vs baseline: 1.0403x; 1.0165x over previous
//
#include <hip/hip_runtime.h>
#include <stdint.h>

// LIF scan: u = 0.5*u + x_t; o = (u > 1); u = 0 where spiked. Bit-exact.
// x: [B=32, T=128, N=8192] fp32; out same, values in {0,1}.
//
// R1-R6 lesson: every drain-to-zero structure (syncthreads => vmcnt(0)) pins
// at 2.4 TB/s; the harness fill (never waits) gets 6.7. The wall is empty
// vmem queues once per chunk, not stores (R6 disproved), not occupancy (R2),
// not block shape (R5). R7: rolling pipeline -- ring of 4 LDS buffers,
// 3 chunks always in flight, raw `s_waitcnt vmcnt(8); s_barrier` via asm
// (compiler's __syncthreads would force vmcnt(0)). Issue(c+3) after the
// barrier that proves consume(c-1) finished in all waves => reuse is safe.
// Spikes bit-packed, burst-stored at the end (keeps stores out of vmcnt
// during the scan). 1024 blocks x 256 thr, 64 KB LDS -> 2 blocks/CU.

constexpr int B    = 32;
constexpr int T    = 128;
constexpr int N    = 8192;
constexpr int N4   = N / 4;      // 2048 float4 per (b,t) row
constexpr int TC   = 16;         // timesteps per staged chunk
constexpr int NC   = T / TC;     // 8 chunks
constexpr int NW4  = 64;         // float4 columns per block = 256 floats
constexpr int RING = 4;          // chunk ring depth (3 in flight + 1 consuming)

__device__ __forceinline__ void async16(void* lds_dst, const void* g_src) {
    __builtin_amdgcn_global_load_lds(
        (const __attribute__((address_space(1))) void*)g_src,
        (__attribute__((address_space(3))) void*)lds_dst, 16, 0, 0);
}

// Wait until own outstanding vmem ops <= vm, then workgroup barrier.
// Raw asm so the compiler does NOT insert its vmcnt(0) drain. Memory
// clobber fences LDS reads/issues across it.
__device__ __forceinline__ void wait_barrier(int vm) {
    if (vm == 8)      asm volatile("s_waitcnt vmcnt(8)\n\ts_barrier" ::: "memory");
    else if (vm == 4) asm volatile("s_waitcnt vmcnt(4)\n\ts_barrier" ::: "memory");
    else              asm volatile("s_waitcnt vmcnt(0)\n\ts_barrier" ::: "memory");
}

__global__ __launch_bounds__(256) void lif_kernel(const float4* __restrict__ x,
                                                  float* __restrict__ out) {
    __shared__ float4 buf[RING][TC][NW4];         // 4 x 16 KB = 64 KB

    const int tid   = threadIdx.x;
    const int wave  = tid >> 6;
    const int lane  = tid & 63;
    const int b     = blockIdx.x >> 5;            // 32 n-tiles per batch row
    const int ntile = blockIdx.x & 31;
    const size_t xbase4 = (size_t)b * T * N4 + (size_t)ntile * NW4;   // float4 units
    const size_t obase  = (size_t)b * T * N  + (size_t)ntile * (NW4 * 4) + tid;
    const float4* gx = x + xbase4;

    // ramp: issue chunks 0..2 (12 outstanding ops per wave, 48 KB per block)
    #pragma unroll
    for (int c = 0; c < 3; ++c) {
        #pragma unroll
        for (int k = 0; k < 4; ++k) {
            const int t_sub = k * 4 + wave;
            async16(&buf[c][t_sub][lane], gx + (size_t)(c * TC + t_sub) * N4 + lane);
        }
    }

    float u = 0.f;
    uint32_t sw[4] = {0u, 0u, 0u, 0u};            // 128 spike bits

    #pragma unroll
    for (int c = 0; c < NC; ++c) {
        // issued chunks at entry: c .. min(c+2, NC-1). Wait for own chunk-c
        // loads (oldest 4), keeping the rest in flight. Barrier also proves
        // all waves finished consuming chunk c-1 -> issue(c+3) reuse is safe.
        const int last = (c + 2 < NC - 1) ? (c + 2) : (NC - 1);
        wait_barrier(4 * (last - c));             // 8,8,8,8,8,8,4,0 across c

        if (c + 3 < NC) {                          // issue chunk c+3
            #pragma unroll
            for (int k = 0; k < 4; ++k) {
                const int t_sub = k * 4 + wave;
                async16(&buf[(c + 3) & (RING - 1)][t_sub][lane],
                        gx + (size_t)((c + 3) * TC + t_sub) * N4 + lane);
            }
        }

        const float* lb = (const float*)buf[c & (RING - 1)];
        #pragma unroll
        for (int t = 0; t < TC; ++t) {            // no global stores in scan
            const float xt = lb[t * 256 + tid];   // lane-local, 2-way alias (free)
            u = 0.5f * u + xt;
            const uint32_t bit = (u > 1.0f) ? 1u : 0u;
            sw[c >> 1] |= bit << ((c & 1) * 16 + t);   // bit index == global t
            u = (u > 1.0f) ? 0.0f : u;
        }
    }

    // burst store: 128 independent coalesced 256B stores per wave
    #pragma unroll
    for (int t = 0; t < T; ++t) {
        const float sp = ((sw[t >> 5] >> (t & 31)) & 1u) ? 1.0f : 0.0f;
        out[obase + (size_t)t * N] = sp;
    }
}

extern "C" void kernel_launch(void* const* d_in, const int* in_sizes, int n_in,
                              void* d_out, int out_size, void* d_ws, size_t ws_size,
                              hipStream_t stream) {
    const float4* x  = (const float4*)d_in[0];
    float*      out = (float*)d_out;
    const int nblocks = B * (N / (NW4 * 4));      // 32 * 32 = 1024
    lif_kernel<<<nblocks, 256, 0, stream>>>(x, out);
}